// Round 13
// baseline (79.100 us; speedup 1.0000x reference)
//
#include <hip/hip_runtime.h>

#define BB 32
#define PP 8000
#define GG 100
#define PT 8100            // P + G
#define NSEL 512
#define POSCAP 128
#define OFF_LAB 65536      // 32*512*4
#define OFF_REG 81920      // OFF_LAB + 32*512
#define NT1 256
#define NT2 1024           // select: 16 waves
#define NWAVE 16
#define SPAN 512           // span per wave; lane owns 8 consecutive keys
#define KPL 8              // keys per lane (SPAN/64)
#define HB 4096            // histogram bins (top 12 of 23 key bits)
#define GCAP 512           // gather buffer cap per group

__device__ __forceinline__ unsigned rotl32(unsigned x, int r) {
  return (x << r) | (x >> (32 - r));
}

// Threefry-2x32, 20 rounds. JAX partitionable 32-bit stream for key(42):
// counter i (uint64) -> x0 = hi(i)=0, x1 = lo(i)=i; key=(0,42); bits = out0^out1
__device__ __forceinline__ unsigned threefry_bits(unsigned ctr) {
  const unsigned k0 = 0u, k1 = 42u;
  const unsigned k2 = k0 ^ k1 ^ 0x1BD11BDAu;
  unsigned x0 = 0u + k0;
  unsigned x1 = ctr + k1;
#define TF4(a,b,c,d) \
  x0 += x1; x1 = rotl32(x1,(a)); x1 ^= x0; \
  x0 += x1; x1 = rotl32(x1,(b)); x1 ^= x0; \
  x0 += x1; x1 = rotl32(x1,(c)); x1 ^= x0; \
  x0 += x1; x1 = rotl32(x1,(d)); x1 ^= x0;
  TF4(13,15,26, 6)  x0 += k1; x1 += k2 + 1u;
  TF4(17,29,16,24)  x0 += k2; x1 += k0 + 2u;
  TF4(13,15,26, 6)  x0 += k0; x1 += k1 + 3u;
  TF4(17,29,16,24)  x0 += k1; x1 += k2 + 4u;
  TF4(13,15,26, 6)  x0 += k2; x1 += k0 + 5u;
#undef TF4
  return x0 ^ x1;
}

// Kernel 1: per (b,t): IoU argmax over G gts -> cls, midx, threefry key.
__global__ __launch_bounds__(NT1) void label_kernel(
    const float* __restrict__ proposals,
    const float* __restrict__ gt_boxes,
    const int*   __restrict__ gt_labels,
    unsigned*    __restrict__ packed,
    unsigned char* __restrict__ midxv)
{
  const int b = blockIdx.y;
  const int t = blockIdx.x * NT1 + threadIdx.x;

  __shared__ float4 sgq[GG];
  __shared__ float  sarea[GG];
  __shared__ int    slab[GG];
  if (threadIdx.x < GG) {
    int g = threadIdx.x;
    float4 q = ((const float4*)gt_boxes)[(size_t)b * GG + g];
    sgq[g] = q;
    sarea[g] = (q.z - q.x) * (q.w - q.y);  // same op order as reference
    slab[g] = gt_labels[b * GG + g];
  }
  __syncthreads();
  if (t >= PT) return;

  float4 p = (t < PP) ? ((const float4*)proposals)[(size_t)b * PP + t]
                      : ((const float4*)gt_boxes)[(size_t)b * GG + (t - PP)];
  float area_p = (p.z - p.x) * (p.w - p.y);
  asm volatile("" : "+v"(area_p));         // block FMA contraction into sum

  float best = -1.0f;
  int bidx = 0;
#pragma unroll 4
  for (int g = 0; g < GG; ++g) {
    float4 q = sgq[g];
    float w = fminf(q.z, p.z) - fmaxf(q.x, p.x);
    float h = fminf(q.w, p.w) - fmaxf(q.y, p.y);
    w = fmaxf(w, 0.0f);
    h = fmaxf(h, 0.0f);
    float inter = w * h;
    asm volatile("" : "+v"(inter));        // block FMA contraction into union
    float uni = (sarea[g] + area_p) - inter;
    float iou = inter / uni;
    if (iou > best) { best = iou; bidx = g; }   // first-max == jnp argmax
  }

  int cls, m;
  if (best < 0.5f) { cls = 0; m = 0; }
  else             { cls = slab[bidx]; m = bidx; }

  unsigned bits = threefry_bits((unsigned)(b * PT + t));
  packed[(size_t)b * PT + t] = (bits >> 9) | ((unsigned)cls << 24);
  midxv[(size_t)b * PT + t] = (unsigned char)m;
}

// Kernel 2: one block (16 waves) per image. IDENTICAL to round 12.
// NOTE: this kernel is idempotent (pure function of packed/midxv -> out),
// so the launcher runs it 3x this round to measure its duration by
// subtraction: T_select = (dur_total - dur_R12) / 2.
__global__ __launch_bounds__(NT2) void select_kernel(
    const float*    __restrict__ proposals,
    const float*    __restrict__ gt_boxes,
    const unsigned* __restrict__ packed,
    const unsigned char* __restrict__ midxv,
    float* __restrict__ out)
{
  const int b = blockIdx.x;
  const int tid = threadIdx.x;
  const int lane = tid & 63;
  const int wid = tid >> 6;
  const unsigned long long laneLT = (1ull << lane) - 1ull;  // lanes strictly below

  __shared__ unsigned hist[HB];        // pos count low16 | neg count high16
  __shared__ unsigned waveTot[NWAVE];
  __shared__ unsigned wHard[NWAVE], wTP[NWAVE], wTN[NWAVE];
  __shared__ unsigned gbufP[GCAP], gbufN[GCAP];
  __shared__ unsigned sBin[2], sAbove[2], sTheta[2], sM[2], sCnt[2];

  // lane owns elements t = s0 + lane*8 + j (lane-major index order)
  const int s0 = wid * SPAN;
  const int tBase = s0 + lane * KPL;
  unsigned k[KPL];
  {
    const uint4* pk4 = (const uint4*)(packed + (size_t)b * PT);
    uint4 va = pk4[(s0 >> 2) + lane * 2];
    uint4 vb = pk4[(s0 >> 2) + lane * 2 + 1];
    k[0]=va.x; k[1]=va.y; k[2]=va.z; k[3]=va.w;
    k[4]=vb.x; k[5]=vb.y; k[6]=vb.z; k[7]=vb.w;
  }

  // zero hist
#pragma unroll
  for (int i = 0; i < HB / NT2; ++i) hist[tid + i * NT2] = 0u;
  __syncthreads();                     // B1

  // histogram on top 12 bits of the 23-bit key (from registers)
#pragma unroll
  for (int j = 0; j < KPL; ++j) {
    if (tBase + j < PT)
      atomicAdd(&hist[(k[j] & 0x7FFFFFu) >> 11],
                (k[j] >> 24) >= 1u ? 1u : 0x10000u);
  }
  __syncthreads();                     // B2

  // block suffix-scan over per-thread 4-bin sums (packed)
  const int BPT = HB / NT2;            // 4 bins per thread
  unsigned local = 0;
#pragma unroll
  for (int j = 0; j < BPT; ++j) local += hist[tid * BPT + j];
  unsigned suf = local;
  for (int d = 1; d < 64; d <<= 1) {
    unsigned o = __shfl_down(suf, d, 64);
    if (lane + d < 64) suf += o;
  }
  if (lane == 0) waveTot[wid] = suf;   // whole-wave sum
  if (tid < 2) sCnt[tid] = 0u;
  __syncthreads();                     // B3

  // totals, caps, locate threshold bins
  unsigned totAll = 0, waveAfter = 0;
#pragma unroll
  for (int w = 0; w < NWAVE; ++w) { unsigned x = waveTot[w]; totAll += x; if (w > wid) waveAfter += x; }
  unsigned num_pos = totAll & 0xFFFFu, num_neg = totAll >> 16;
  bool allP = (num_pos <= POSCAP);
  unsigned capP = allP ? num_pos : POSCAP;
  unsigned Kneg = NSEL - capP;
  bool allN = (num_neg <= Kneg);
  unsigned sumAfter = waveAfter + (suf - local);  // threads strictly after me
  {
    unsigned aP = sumAfter & 0xFFFFu, aN = sumAfter >> 16;
#pragma unroll
    for (int j = BPT - 1; j >= 0; --j) {
      unsigned hc = hist[tid * BPT + j];
      unsigned hp = hc & 0xFFFFu, hn = hc >> 16;
      if (!allP && aP < POSCAP && aP + hp >= POSCAP) { sBin[0] = tid * BPT + j; sAbove[0] = aP; }
      if (!allN && aN < Kneg   && aN + hn >= Kneg)   { sBin[1] = tid * BPT + j; sAbove[1] = aN; }
      aP += hp; aN += hn;
    }
  }
  __syncthreads();                     // B4

  // gather members of the threshold bins (from registers)
  unsigned binP = sBin[0], binN = sBin[1];
#pragma unroll
  for (int j = 0; j < KPL; ++j) {
    if (tBase + j < PT) {
      unsigned key = k[j] & 0x7FFFFFu;
      bool isP = (k[j] >> 24) >= 1u;
      if (!allP && isP && (key >> 11) == binP) {
        unsigned i = atomicAdd(&sCnt[0], 1u);
        if (i < GCAP) gbufP[i] = key;
      }
      if (!allN && !isP && (key >> 11) == binN) {
        unsigned i = atomicAdd(&sCnt[1], 1u);
        if (i < GCAP) gbufN[i] = key;
      }
    }
  }
  __syncthreads();                     // B5

  // exact in-bin rank resolve (wave 0: pos, wave 1: neg)
  if (wid == 0 && !allP) {
    int n = min((int)sCnt[0], GCAP);
    unsigned above = sAbove[0];
    unsigned r = POSCAP - above;       // 1-indexed rank within bin
    for (int i = lane; i < n; i += 64) {
      unsigned ki = gbufP[i];
      unsigned gt = 0, ge = 0;
      for (int j = 0; j < n; ++j) { unsigned kj = gbufP[j]; gt += (kj > ki); ge += (kj >= ki); }
      if (gt < r && ge >= r) { sTheta[0] = ki; sM[0] = POSCAP - (above + gt); }
    }
  }
  if (wid == 1 && !allN) {
    int n = min((int)sCnt[1], GCAP);
    unsigned above = sAbove[1];
    unsigned r = Kneg - above;
    for (int i = lane; i < n; i += 64) {
      unsigned ki = gbufN[i];
      unsigned gt = 0, ge = 0;
      for (int j = 0; j < n; ++j) { unsigned kj = gbufN[j]; gt += (kj > ki); ge += (kj >= ki); }
      if (gt < r && ge >= r) { sTheta[1] = ki; sM[1] = Kneg - (above + gt); }
    }
  }
  __syncthreads();                     // B6

  unsigned thetaP = allP ? 0u : sTheta[0];
  unsigned mP     = allP ? 0u : sM[0];
  unsigned thetaN = allN ? 0u : sTheta[1];
  unsigned mN     = allN ? 0u : sM[1];

  // pass 1: per-lane 8-bit flag masks + wave totals via ballots
  unsigned myHard = 0, myTP = 0, myTN = 0;
#pragma unroll
  for (int j = 0; j < KPL; ++j) {
    if (tBase + j < PT) {
      unsigned key = k[j] & 0x7FFFFFu;
      if ((k[j] >> 24) >= 1u) {
        if (allP || key > thetaP) myHard |= 1u << j;
        else if (key == thetaP)   myTP |= 1u << j;
      } else {
        if (allN || key > thetaN) myHard |= 1u << j;
        else if (key == thetaN)   myTN |= 1u << j;
      }
    }
  }
  unsigned hardCnt = 0, tpCnt = 0, tnCnt = 0;
#pragma unroll
  for (int j = 0; j < KPL; ++j) {
    hardCnt += __popcll(__ballot((myHard >> j) & 1u));
    tpCnt   += __popcll(__ballot((myTP   >> j) & 1u));
    tnCnt   += __popcll(__ballot((myTN   >> j) & 1u));
  }
  if (lane == 0) { wHard[wid] = hardCnt; wTP[wid] = tpCnt; wTN[wid] = tnCnt; }
  __syncthreads();                     // B7

  // per-wave bases (ties taken in global index order -> analytic)
  unsigned tieBaseP = 0, tieBaseN = 0, posBase = 0;
  {
    unsigned tb = 0, nb = 0;
#pragma unroll
    for (int w = 0; w < NWAVE; ++w) {
      if (w == wid) { tieBaseP = tb; tieBaseN = nb; break; }
      unsigned takeP = (mP > tb) ? min(mP - tb, wTP[w]) : 0u;
      unsigned takeN = (mN > nb) ? min(mN - nb, wTN[w]) : 0u;
      posBase += wHard[w] + takeP + takeN;
      tb += wTP[w]; nb += wTN[w];
    }
  }

  // pass 2: tie ranks + selection + positions, then batched epilogue gathers.
  {
    unsigned long long mtp[KPL], mtn[KPL];
#pragma unroll
    for (int j = 0; j < KPL; ++j) {
      mtp[j] = __ballot((myTP >> j) & 1u);
      mtn[j] = __ballot((myTN >> j) & 1u);
    }
    unsigned basTP = tieBaseP, basTN = tieBaseN;
#pragma unroll
    for (int j = 0; j < KPL; ++j) {
      basTP += __popcll(mtp[j] & laneLT);
      basTN += __popcll(mtn[j] & laneLT);
    }
    unsigned mySel = 0, prefTP = 0, prefTN = 0;
#pragma unroll
    for (int j = 0; j < KPL; ++j) {
      bool s = (myHard >> j) & 1u;
      if ((myTP >> j) & 1u) { s = (basTP + prefTP) < mP; prefTP++; }
      if ((myTN >> j) & 1u) { s = (basTN + prefTN) < mN; prefTN++; }
      if (s) mySel |= 1u << j;
    }
    unsigned posAcc = posBase;
#pragma unroll
    for (int j = 0; j < KPL; ++j)
      posAcc += __popcll(__ballot((mySel >> j) & 1u) & laneLT);

    unsigned posj[KPL];
    {
      unsigned prefSel = 0;
#pragma unroll
      for (int j = 0; j < KPL; ++j) {
        posj[j] = posAcc + prefSel;
        if ((mySel >> j) & 1u) prefSel++;
      }
    }

    float4 pj[KPL];
    int    mj[KPL];
#pragma unroll
    for (int j = 0; j < KPL; ++j) {
      if ((mySel >> j) & 1u) {
        int t = tBase + j;
        pj[j] = (t < PP) ? ((const float4*)proposals)[(size_t)b * PP + t]
                         : ((const float4*)gt_boxes)[(size_t)b * GG + (t - PP)];
        mj[j] = midxv[(size_t)b * PT + t];
      }
    }
    float4 gqj[KPL];
#pragma unroll
    for (int j = 0; j < KPL; ++j) {
      if ((mySel >> j) & 1u)
        gqj[j] = ((const float4*)gt_boxes)[(size_t)b * GG + mj[j]];
    }
#pragma unroll
    for (int j = 0; j < KPL; ++j) {
      if ((mySel >> j) & 1u) {
        unsigned cls = k[j] >> 24;
        float4 p = pj[j];
        float4 gq = gqj[j];
        size_t o1 = (size_t)b * NSEL + posj[j];
        out[o1 * 4 + 0] = p.x;
        out[o1 * 4 + 1] = p.y;
        out[o1 * 4 + 2] = p.z;
        out[o1 * 4 + 3] = p.w;
        out[OFF_LAB + o1] = (float)cls;

        float pw = p.z - p.x, ph = p.w - p.y;
        float px = p.x + 0.5f * pw, py = p.y + 0.5f * ph;
        float gw = gq.z - gq.x, gh = gq.w - gq.y;
        float gx = gq.x + 0.5f * gw, gy = gq.y + 0.5f * gh;
        size_t o2 = OFF_REG + o1 * 4;
        out[o2 + 0] = 10.0f * (gx - px) / pw;
        out[o2 + 1] = 10.0f * (gy - py) / ph;
        out[o2 + 2] = 5.0f * logf(gw / pw);
        out[o2 + 3] = 5.0f * logf(gh / ph);
      }
    }
  }
}

extern "C" void kernel_launch(void* const* d_in, const int* in_sizes, int n_in,
                              void* d_out, int out_size, void* d_ws, size_t ws_size,
                              hipStream_t stream) {
  const float* proposals = (const float*)d_in[0];
  const float* gt_boxes  = (const float*)d_in[1];
  const int*   gt_labels = (const int*)d_in[2];
  float* out = (float*)d_out;

  unsigned* packed = (unsigned*)d_ws;
  unsigned char* midxv = (unsigned char*)d_ws + (size_t)BB * PT * sizeof(unsigned);

  dim3 g1((PT + NT1 - 1) / NT1, BB);
  label_kernel<<<g1, NT1, 0, stream>>>(proposals, gt_boxes, gt_labels, packed, midxv);
  // MEASUREMENT ROUND: select is idempotent (pure packed/midxv -> out).
  // Run 3x; T_select = (dur_total - dur_R12) / 2. Output unchanged.
  select_kernel<<<BB, NT2, 0, stream>>>(proposals, gt_boxes, packed, midxv, out);
  select_kernel<<<BB, NT2, 0, stream>>>(proposals, gt_boxes, packed, midxv, out);
  select_kernel<<<BB, NT2, 0, stream>>>(proposals, gt_boxes, packed, midxv, out);
}

// Round 14
// 43.545 us; speedup vs baseline: 1.8165x; 1.8165x over previous
//
#include <hip/hip_runtime.h>

#define BB 32
#define PP 8000
#define GG 100
#define PT 8100            // P + G
#define NSEL 512
#define POSCAP 128
#define OFF_LAB 65536      // 32*512*4
#define OFF_REG 81920      // OFF_LAB + 32*512
#define NT1 256
#define NT2 1024           // select: 16 waves
#define NWAVE 16
#define SPAN 512           // span per wave; lane owns 8 consecutive keys
#define KPL 8              // keys per lane (SPAN/64)
#define HB 4096            // histogram bins (top 12 of 23 key bits)
#define GCAP 512           // gather buffer cap per group

__device__ __forceinline__ unsigned rotl32(unsigned x, int r) {
  return (x << r) | (x >> (32 - r));
}

// Threefry-2x32, 20 rounds. JAX partitionable 32-bit stream for key(42):
// counter i (uint64) -> x0 = hi(i)=0, x1 = lo(i)=i; key=(0,42); bits = out0^out1
__device__ __forceinline__ unsigned threefry_bits(unsigned ctr) {
  const unsigned k0 = 0u, k1 = 42u;
  const unsigned k2 = k0 ^ k1 ^ 0x1BD11BDAu;
  unsigned x0 = 0u + k0;
  unsigned x1 = ctr + k1;
#define TF4(a,b,c,d) \
  x0 += x1; x1 = rotl32(x1,(a)); x1 ^= x0; \
  x0 += x1; x1 = rotl32(x1,(b)); x1 ^= x0; \
  x0 += x1; x1 = rotl32(x1,(c)); x1 ^= x0; \
  x0 += x1; x1 = rotl32(x1,(d)); x1 ^= x0;
  TF4(13,15,26, 6)  x0 += k1; x1 += k2 + 1u;
  TF4(17,29,16,24)  x0 += k2; x1 += k0 + 2u;
  TF4(13,15,26, 6)  x0 += k0; x1 += k1 + 3u;
  TF4(17,29,16,24)  x0 += k1; x1 += k2 + 4u;
  TF4(13,15,26, 6)  x0 += k2; x1 += k0 + 5u;
#undef TF4
  return x0 ^ x1;
}

// Kernel 1: per (b,t): IoU argmax over G gts -> cls, midx, threefry key.
__global__ __launch_bounds__(NT1) void label_kernel(
    const float* __restrict__ proposals,
    const float* __restrict__ gt_boxes,
    const int*   __restrict__ gt_labels,
    unsigned*    __restrict__ packed,
    unsigned char* __restrict__ midxv)
{
  const int b = blockIdx.y;
  const int t = blockIdx.x * NT1 + threadIdx.x;

  __shared__ float4 sgq[GG];
  __shared__ float  sarea[GG];
  __shared__ int    slab[GG];
  if (threadIdx.x < GG) {
    int g = threadIdx.x;
    float4 q = ((const float4*)gt_boxes)[(size_t)b * GG + g];
    sgq[g] = q;
    sarea[g] = (q.z - q.x) * (q.w - q.y);  // same op order as reference
    slab[g] = gt_labels[b * GG + g];
  }
  __syncthreads();
  if (t >= PT) return;

  float4 p = (t < PP) ? ((const float4*)proposals)[(size_t)b * PP + t]
                      : ((const float4*)gt_boxes)[(size_t)b * GG + (t - PP)];
  float area_p = (p.z - p.x) * (p.w - p.y);
  asm volatile("" : "+v"(area_p));         // block FMA contraction into sum

  float best = -1.0f;
  int bidx = 0;
#pragma unroll 4
  for (int g = 0; g < GG; ++g) {
    float4 q = sgq[g];
    float w = fminf(q.z, p.z) - fmaxf(q.x, p.x);
    float h = fminf(q.w, p.w) - fmaxf(q.y, p.y);
    w = fmaxf(w, 0.0f);
    h = fmaxf(h, 0.0f);
    float inter = w * h;
    asm volatile("" : "+v"(inter));        // block FMA contraction into union
    float uni = (sarea[g] + area_p) - inter;
    float iou = inter / uni;
    if (iou > best) { best = iou; bidx = g; }   // first-max == jnp argmax
  }

  int cls, m;
  if (best < 0.5f) { cls = 0; m = 0; }
  else             { cls = slab[bidx]; m = bidx; }

  unsigned bits = threefry_bits((unsigned)(b * PT + t));
  packed[(size_t)b * PT + t] = (bits >> 9) | ((unsigned)cls << 24);
  midxv[(size_t)b * PT + t] = (unsigned char)m;
}

// Kernel 2: one block (16 waves) per image. Keys in registers (8/lane).
// Ranks via per-lane popcount + one shfl_up wave scan per flag type
// (replaces ~56 ballot+popcll ops); lean epilogue (low VGPR).
__global__ __launch_bounds__(NT2) void select_kernel(
    const float*    __restrict__ proposals,
    const float*    __restrict__ gt_boxes,
    const unsigned* __restrict__ packed,
    const unsigned char* __restrict__ midxv,
    float* __restrict__ out)
{
  const int b = blockIdx.x;
  const int tid = threadIdx.x;
  const int lane = tid & 63;
  const int wid = tid >> 6;

  __shared__ unsigned hist[HB];        // pos count low16 | neg count high16
  __shared__ unsigned waveTot[NWAVE];
  __shared__ unsigned wHard[NWAVE], wTP[NWAVE], wTN[NWAVE];
  __shared__ unsigned gbufP[GCAP], gbufN[GCAP];
  __shared__ unsigned sBin[2], sAbove[2], sTheta[2], sM[2], sCnt[2];

  auto waveIncScan = [&](unsigned v) -> unsigned {   // inclusive over 64 lanes
    for (int d = 1; d < 64; d <<= 1) {
      unsigned o = __shfl_up(v, d, 64);
      if (lane >= d) v += o;
    }
    return v;
  };

  // lane owns elements t = s0 + lane*8 + j (lane-major index order)
  const int s0 = wid * SPAN;
  const int tBase = s0 + lane * KPL;
  unsigned k[KPL];
  {
    const uint4* pk4 = (const uint4*)(packed + (size_t)b * PT);
    uint4 va = pk4[(s0 >> 2) + lane * 2];
    uint4 vb = pk4[(s0 >> 2) + lane * 2 + 1];
    k[0]=va.x; k[1]=va.y; k[2]=va.z; k[3]=va.w;
    k[4]=vb.x; k[5]=vb.y; k[6]=vb.z; k[7]=vb.w;
  }

  // zero hist
#pragma unroll
  for (int i = 0; i < HB / NT2; ++i) hist[tid + i * NT2] = 0u;
  __syncthreads();                     // B1

  // histogram on top 12 bits of the 23-bit key (from registers)
#pragma unroll
  for (int j = 0; j < KPL; ++j) {
    if (tBase + j < PT)
      atomicAdd(&hist[(k[j] & 0x7FFFFFu) >> 11],
                (k[j] >> 24) >= 1u ? 1u : 0x10000u);
  }
  __syncthreads();                     // B2

  // block suffix-scan over per-thread 4-bin sums (packed)
  const int BPT = HB / NT2;            // 4 bins per thread
  unsigned local = 0;
#pragma unroll
  for (int j = 0; j < BPT; ++j) local += hist[tid * BPT + j];
  unsigned suf = local;
  for (int d = 1; d < 64; d <<= 1) {
    unsigned o = __shfl_down(suf, d, 64);
    if (lane + d < 64) suf += o;
  }
  if (lane == 0) waveTot[wid] = suf;   // whole-wave sum
  if (tid < 2) sCnt[tid] = 0u;
  __syncthreads();                     // B3

  // totals, caps, locate threshold bins
  unsigned totAll = 0, waveAfter = 0;
#pragma unroll
  for (int w = 0; w < NWAVE; ++w) { unsigned x = waveTot[w]; totAll += x; if (w > wid) waveAfter += x; }
  unsigned num_pos = totAll & 0xFFFFu, num_neg = totAll >> 16;
  bool allP = (num_pos <= POSCAP);
  unsigned capP = allP ? num_pos : POSCAP;
  unsigned Kneg = NSEL - capP;
  bool allN = (num_neg <= Kneg);
  unsigned sumAfter = waveAfter + (suf - local);  // threads strictly after me
  {
    unsigned aP = sumAfter & 0xFFFFu, aN = sumAfter >> 16;
#pragma unroll
    for (int j = BPT - 1; j >= 0; --j) {
      unsigned hc = hist[tid * BPT + j];
      unsigned hp = hc & 0xFFFFu, hn = hc >> 16;
      if (!allP && aP < POSCAP && aP + hp >= POSCAP) { sBin[0] = tid * BPT + j; sAbove[0] = aP; }
      if (!allN && aN < Kneg   && aN + hn >= Kneg)   { sBin[1] = tid * BPT + j; sAbove[1] = aN; }
      aP += hp; aN += hn;
    }
  }
  __syncthreads();                     // B4

  // gather members of the threshold bins (from registers)
  unsigned binP = sBin[0], binN = sBin[1];
#pragma unroll
  for (int j = 0; j < KPL; ++j) {
    if (tBase + j < PT) {
      unsigned key = k[j] & 0x7FFFFFu;
      bool isP = (k[j] >> 24) >= 1u;
      if (!allP && isP && (key >> 11) == binP) {
        unsigned i = atomicAdd(&sCnt[0], 1u);
        if (i < GCAP) gbufP[i] = key;
      }
      if (!allN && !isP && (key >> 11) == binN) {
        unsigned i = atomicAdd(&sCnt[1], 1u);
        if (i < GCAP) gbufN[i] = key;
      }
    }
  }
  __syncthreads();                     // B5

  // exact in-bin rank resolve (wave 0: pos, wave 1: neg)
  if (wid == 0 && !allP) {
    int n = min((int)sCnt[0], GCAP);
    unsigned above = sAbove[0];
    unsigned r = POSCAP - above;       // 1-indexed rank within bin
    for (int i = lane; i < n; i += 64) {
      unsigned ki = gbufP[i];
      unsigned gt = 0, ge = 0;
      for (int j = 0; j < n; ++j) { unsigned kj = gbufP[j]; gt += (kj > ki); ge += (kj >= ki); }
      if (gt < r && ge >= r) { sTheta[0] = ki; sM[0] = POSCAP - (above + gt); }
    }
  }
  if (wid == 1 && !allN) {
    int n = min((int)sCnt[1], GCAP);
    unsigned above = sAbove[1];
    unsigned r = Kneg - above;
    for (int i = lane; i < n; i += 64) {
      unsigned ki = gbufN[i];
      unsigned gt = 0, ge = 0;
      for (int j = 0; j < n; ++j) { unsigned kj = gbufN[j]; gt += (kj > ki); ge += (kj >= ki); }
      if (gt < r && ge >= r) { sTheta[1] = ki; sM[1] = Kneg - (above + gt); }
    }
  }
  __syncthreads();                     // B6

  unsigned thetaP = allP ? 0u : sTheta[0];
  unsigned mP     = allP ? 0u : sM[0];
  unsigned thetaN = allN ? 0u : sTheta[1];
  unsigned mN     = allN ? 0u : sM[1];

  // pass 1: per-lane 8-bit flag masks; ranks via popcount + wave scans
  unsigned myHard = 0, myTP = 0, myTN = 0;
#pragma unroll
  for (int j = 0; j < KPL; ++j) {
    if (tBase + j < PT) {
      unsigned key = k[j] & 0x7FFFFFu;
      if ((k[j] >> 24) >= 1u) {
        if (allP || key > thetaP) myHard |= 1u << j;
        else if (key == thetaP)   myTP |= 1u << j;
      } else {
        if (allN || key > thetaN) myHard |= 1u << j;
        else if (key == thetaN)   myTN |= 1u << j;
      }
    }
  }
  unsigned cH = __popc(myHard), cP = __popc(myTP), cN = __popc(myTN);
  unsigned iH = waveIncScan(cH), iP = waveIncScan(cP), iN = waveIncScan(cN);
  if (lane == 63) { wHard[wid] = iH; wTP[wid] = iP; wTN[wid] = iN; }
  __syncthreads();                     // B7

  // per-wave bases (ties taken in global index order -> analytic)
  unsigned tieBaseP = 0, tieBaseN = 0, posBase = 0;
  {
    unsigned tb = 0, nb = 0;
#pragma unroll
    for (int w = 0; w < NWAVE; ++w) {
      if (w == wid) { tieBaseP = tb; tieBaseN = nb; break; }
      unsigned takeP = (mP > tb) ? min(mP - tb, wTP[w]) : 0u;
      unsigned takeN = (mN > nb) ? min(mN - nb, wTN[w]) : 0u;
      posBase += wHard[w] + takeP + takeN;
      tb += wTP[w]; nb += wTN[w];
    }
  }

  // pass 2: selection + positions from lane-exclusive prefixes
  {
    unsigned laneTBP = tieBaseP + iP - cP;   // ties before my lane (pos)
    unsigned laneTBN = tieBaseN + iN - cN;   // ties before my lane (neg)
    unsigned mySel = 0, prefTP = 0, prefTN = 0;
#pragma unroll
    for (int j = 0; j < KPL; ++j) {
      bool s = (myHard >> j) & 1u;
      if ((myTP >> j) & 1u) { s = (laneTBP + prefTP) < mP; prefTP++; }
      if ((myTN >> j) & 1u) { s = (laneTBN + prefTN) < mN; prefTN++; }
      if (s) mySel |= 1u << j;
    }
    unsigned cS = __popc(mySel);
    unsigned iS = waveIncScan(cS);
    unsigned lanePos = posBase + iS - cS;    // output slot of my first selected

    // lean epilogue: batch the tiny midx loads, then per-j pipeline
    int mj[KPL];
#pragma unroll
    for (int j = 0; j < KPL; ++j)
      if ((mySel >> j) & 1u) mj[j] = midxv[(size_t)b * PT + tBase + j];

    unsigned prefSel = 0;
#pragma unroll
    for (int j = 0; j < KPL; ++j) {
      if ((mySel >> j) & 1u) {
        int t = tBase + j;
        unsigned cls = k[j] >> 24;
        unsigned pos = lanePos + prefSel;
        prefSel++;

        float4 p = (t < PP) ? ((const float4*)proposals)[(size_t)b * PP + t]
                            : ((const float4*)gt_boxes)[(size_t)b * GG + (t - PP)];
        float4 gq = ((const float4*)gt_boxes)[(size_t)b * GG + mj[j]];

        size_t o1 = (size_t)b * NSEL + pos;
        out[o1 * 4 + 0] = p.x;
        out[o1 * 4 + 1] = p.y;
        out[o1 * 4 + 2] = p.z;
        out[o1 * 4 + 3] = p.w;
        out[OFF_LAB + o1] = (float)cls;

        float pw = p.z - p.x, ph = p.w - p.y;
        float px = p.x + 0.5f * pw, py = p.y + 0.5f * ph;
        float gw = gq.z - gq.x, gh = gq.w - gq.y;
        float gx = gq.x + 0.5f * gw, gy = gq.y + 0.5f * gh;
        size_t o2 = OFF_REG + o1 * 4;
        out[o2 + 0] = 10.0f * (gx - px) / pw;
        out[o2 + 1] = 10.0f * (gy - py) / ph;
        out[o2 + 2] = 5.0f * logf(gw / pw);
        out[o2 + 3] = 5.0f * logf(gh / ph);
      }
    }
  }
}

extern "C" void kernel_launch(void* const* d_in, const int* in_sizes, int n_in,
                              void* d_out, int out_size, void* d_ws, size_t ws_size,
                              hipStream_t stream) {
  const float* proposals = (const float*)d_in[0];
  const float* gt_boxes  = (const float*)d_in[1];
  const int*   gt_labels = (const int*)d_in[2];
  float* out = (float*)d_out;

  unsigned* packed = (unsigned*)d_ws;
  unsigned char* midxv = (unsigned char*)d_ws + (size_t)BB * PT * sizeof(unsigned);

  dim3 g1((PT + NT1 - 1) / NT1, BB);
  label_kernel<<<g1, NT1, 0, stream>>>(proposals, gt_boxes, gt_labels, packed, midxv);
  select_kernel<<<BB, NT2, 0, stream>>>(proposals, gt_boxes, packed, midxv, out);
}